// Round 5
// baseline (467.776 us; speedup 1.0000x reference)
//
#include <hip/hip_runtime.h>

// ---------------------------------------------------------------------------
// TT linear layer, all I/O fp32: out[8192,4096] = x @ G^T + bias.
// R8 == R7 resubmit (broker timeout; never ran). R7 fixed the REAL
// R4/R5 correctness bug: the schedule's "A0/A1" labels conflated STG
// halves (M rows 0-127 / 128-255) with read quadrants (rows 0-63 /
// 64-127 WITHIN each wave's half): LDA(s,1) reads rows 64-127 of BOTH
// halves at phase 3, but sA[s][0] was staged at phase 2 -> deterministic
// wrong-K data for rows 64-127 (absmax 7.875, reproducible). Fix: stage
// B halves at group-phases 3,4 (free after ph2) and A halves at phases
// 5,6 / next-1,2 (free after ph3); vmcnt(4) at P4/P8 (12 outstanding,
// drain 8 = the tile read next). Full re-audit r8: read map, FIFO walk,
// coverage, register lifetimes all verified.
// gemm: 256x256 8-phase template (m201): BK=64, 8 waves, counted vmcnt,
// raw s_barrier, XOR-swizzled LDS via pre-swizzled DMA source, setprio
// around MFMA, bijective XCD block swizzle.
//   d_ws: [0,32MB) G bf16 [4096,4096]; [32MB,96MB) x bf16 [8192,4096].
// ---------------------------------------------------------------------------

typedef short bf16x8 __attribute__((ext_vector_type(8)));
typedef float f32x4 __attribute__((ext_vector_type(4)));

__device__ __forceinline__ unsigned short f2bf_rne(float f) {
  union { float f; unsigned int i; } v;
  v.f = f;
  unsigned int r = v.i + 0x7FFFu + ((v.i >> 16) & 1u);
  return (unsigned short)(r >> 16);
}

__device__ __forceinline__ unsigned int pk2bf_rne(float lo, float hi) {
  return (unsigned int)f2bf_rne(lo) | ((unsigned int)f2bf_rne(hi) << 16);
}

__device__ __forceinline__ unsigned int pk2bf_trunc(float lo, float hi) {
  union { float f; unsigned int u; } a, b;
  a.f = lo; b.f = hi;
  return (b.u & 0xFFFF0000u) | (a.u >> 16);
}

__device__ __forceinline__ void gl2lds16(const void* g, void* l) {
  __builtin_amdgcn_global_load_lds(
      (__attribute__((address_space(1))) void*)g,
      (__attribute__((address_space(3))) void*)l, 16u, 0, 0u);
}

// ---------------------------------------------------------------------------
// x fp32 -> bf16 (RNE), 8 elems/thread.
// ---------------------------------------------------------------------------
__global__ __launch_bounds__(256) void cvt_x(const float* __restrict__ x,
                                             unsigned short* __restrict__ xb) {
  const size_t t = (size_t)blockIdx.x * 256 + threadIdx.x;
  const float4 a0 = *(const float4*)(x + t * 8);
  const float4 a1 = *(const float4*)(x + t * 8 + 4);
  uint4 w = {pk2bf_rne(a0.x, a0.y), pk2bf_rne(a0.z, a0.w),
             pk2bf_rne(a1.x, a1.y), pk2bf_rne(a1.z, a1.w)};
  *(uint4*)(xb + t * 8) = w;
}

// ---------------------------------------------------------------------------
// build_g (unchanged from R3-passing). Block = (i,j), 256 blocks, 256 thr.
// ---------------------------------------------------------------------------
__global__ __launch_bounds__(256, 1) void build_g(
    const float* __restrict__ core0,   // [1,16,16,16] (i,n,b)
    const float* __restrict__ core1,   // [16,16,16,16] (b,j,m,c)
    const float* __restrict__ core2,   // [16,16,16,1]  (c,k,o)
    unsigned short* __restrict__ G) {  // [4096,4096] bf16
  __shared__ float c0s[256];
  __shared__ float c1s[16 * 320];
  __shared__ float c2s[4096];
  __shared__ float Hs[256 * 20];
  const int t = threadIdx.x;
  const int blk = blockIdx.x;  // i*16 + j
  const int i = blk >> 4, j = blk & 15;

  c0s[t] = core0[i * 256 + t];
  {
    const int m = t >> 4, c = t & 15;
#pragma unroll
    for (int b = 0; b < 16; b++)
      c1s[b * 320 + m * 20 + c] = core1[b * 4096 + j * 256 + t];
  }
#pragma unroll
  for (int q = 0; q < 16; q++) c2s[q * 256 + t] = core2[q * 256 + t];
  __syncthreads();

  {
    const int n = t >> 4, m = t & 15;
    f32x4 hv0 = {0.f, 0.f, 0.f, 0.f}, hv1 = hv0, hv2 = hv0, hv3 = hv0;
#pragma unroll
    for (int b = 0; b < 16; b++) {
      const float a = c0s[n * 16 + b];
      const f32x4* p = (const f32x4*)&c1s[b * 320 + m * 20];
      hv0 += a * p[0];
      hv1 += a * p[1];
      hv2 += a * p[2];
      hv3 += a * p[3];
    }
    f32x4* hp = (f32x4*)&Hs[t * 20];
    hp[0] = hv0; hp[1] = hv1; hp[2] = hv2; hp[3] = hv3;
  }
  __syncthreads();

  const int w = t >> 6, l = t & 63;
  f32x4 hr[4][4];
#pragma unroll
  for (int q = 0; q < 4; q++) {
    const f32x4* hp = (const f32x4*)&Hs[(l + 64 * q) * 20];
#pragma unroll
    for (int d = 0; d < 4; d++) hr[q][d] = hp[d];
  }

#pragma unroll
  for (int kk = 0; kk < 4; kk++) {
    const int k = w * 4 + kk;
    f32x4 acc[4][4];
    const f32x4 zero = {0.f, 0.f, 0.f, 0.f};
#pragma unroll
    for (int q = 0; q < 4; q++)
#pragma unroll
      for (int d = 0; d < 4; d++) acc[q][d] = zero;

#pragma unroll
    for (int c = 0; c < 16; c++) {
      const f32x4* cp = (const f32x4*)&c2s[c * 256 + k * 16];
      const f32x4 cv0 = cp[0], cv1 = cp[1], cv2 = cp[2], cv3 = cp[3];
#pragma unroll
      for (int q = 0; q < 4; q++) {
        const float hqc = hr[q][c >> 2][c & 3];
        acc[q][0] += hqc * cv0;
        acc[q][1] += hqc * cv1;
        acc[q][2] += hqc * cv2;
        acc[q][3] += hqc * cv3;
      }
    }

    const size_t rowbase = (size_t)(blk * 16 + k) * 4096;
#pragma unroll
    for (int q = 0; q < 4; q++) {
      unsigned int u[8];
#pragma unroll
      for (int d = 0; d < 8; d++)
        u[d] = pk2bf_rne(acc[q][d >> 1][(d & 1) * 2],
                         acc[q][d >> 1][(d & 1) * 2 + 1]);
      uint4* gp = (uint4*)&G[rowbase + (size_t)(l + 64 * q) * 16];
      uint4 s0 = {u[0], u[1], u[2], u[3]};
      uint4 s1 = {u[4], u[5], u[6], u[7]};
      gp[0] = s0;
      gp[1] = s1;
    }
  }
}

// ---------------------------------------------------------------------------
constexpr int Mdim = 8192, Ndim = 4096, Kdim = 4096;

// ---------------------------------------------------------------------------
// 8-phase 256x256 GEMM (m201 template, plain HIP).
// C[M,N] = A[M,K] * Bt[N,K]^T + bias. A,Bt bf16, fp32 out.
// 512 thr / 8 waves (2Mx4N). LDS: [slot][half][128][64] bf16 per matrix.
// Region-read map (ground truth):
//   sA[s][h]: read at group-phase 1 (rows 0-63, by wm==h waves) AND
//             group-phase 3 (rows 64-127) -> free for restage at phase 4+.
//   sB[s][h]: fully read by end of group-phase 2 -> free at phase 3+.
// Stage placement honors this: B halves at phases 3,4; A halves at 5,6
// (slot0) / next-iter 1,2 (slot1). vmcnt(4) at P4/P8: 12 outstanding,
// drain oldest 8 = exactly the tile read in the following 4 phases.
// Swizzle: phys k-slot p at row r holds logical p^(r&7) (both-sides
// involution, rule 21); banks 2-way (free).
// ---------------------------------------------------------------------------
__global__ __launch_bounds__(512, 2) void gemm_8ph(
    const unsigned short* __restrict__ A,     // [M,K] bf16
    const unsigned short* __restrict__ Bt,    // [N,K] bf16
    const float* __restrict__ bias,           // [N]
    float* __restrict__ C) {                  // [M,N] fp32
  __shared__ __align__(16) unsigned short sA[2][2][8192];  // [slot][half][128*64]
  __shared__ __align__(16) unsigned short sB[2][2][8192];

  const int tid = threadIdx.x, lane = tid & 63, wave = tid >> 6;
  const int wm = wave >> 2, wn = wave & 3;  // 2 x 4 wave grid

  // bijective XCD swizzle: 512 blocks, 64 consecutive per XCD
  const int bid = (int)blockIdx.x;
  const int swz = (bid & 7) * 64 + (bid >> 3);
  const int bm0 = (swz >> 4) * 256, bn0 = (swz & 15) * 256;

  // ---- staging: lane l covers (row = 8*wave + (l>>3), phys slot l&7),
  // source k-slot = (l&7)^(l>>3) so LDS phys slot p holds logical p^(row&7).
  const int srow = 8 * wave + (lane >> 3);
  const int scol = ((lane & 7) ^ (lane >> 3)) * 8;  // elements
  const unsigned short* Ag = A + (size_t)(bm0 + srow) * Kdim + scol;
  const unsigned short* Bg = Bt + (size_t)(bn0 + srow) * Kdim + scol;
  unsigned short* Asl = &sA[0][0][0] + wave * 512 + lane * 8;
  unsigned short* Bsl = &sB[0][0][0] + wave * 512 + lane * 8;

#define STG_A(slot, half, kt)                                                  \
  do {                                                                         \
    gl2lds16(Ag + (size_t)(128 * (half)) * Kdim + (kt) * 64,                   \
             Asl + (slot) * 16384 + (half) * 8192);                            \
    gl2lds16(Ag + (size_t)(128 * (half) + 64) * Kdim + (kt) * 64,              \
             Asl + (slot) * 16384 + (half) * 8192 + 4096);                     \
  } while (0)
#define STG_B(slot, half, kt)                                                  \
  do {                                                                         \
    gl2lds16(Bg + (size_t)(128 * (half)) * Kdim + (kt) * 64,                   \
             Bsl + (slot) * 16384 + (half) * 8192);                            \
    gl2lds16(Bg + (size_t)(128 * (half) + 64) * Kdim + (kt) * 64,              \
             Bsl + (slot) * 16384 + (half) * 8192 + 4096);                     \
  } while (0)

  // ---- fragment reads: row = (group)*16 + (lane&15) -> row&7 == lane&7.
  const int r15 = lane & 15, quad = lane >> 4;
  const int cs0 = ((quad) ^ (lane & 7)) * 8;      // ks=0 phys col (shorts)
  const int cs1 = ((4 + quad) ^ (lane & 7)) * 8;  // ks=1
  const unsigned short* Ard = &sA[0][wm][0] + r15 * 64;
  const unsigned short* Brd = &sB[0][wn >> 1][0] + ((wn & 1) * 64 + r15) * 64;

  bf16x8 afr[4][2];  // current A-quadrant: [m][ks]
  bf16x8 bfr[4][2];  // all 4 N-frags: [nf][ks]
  f32x4 acc[8][4];   // [a*4+m][nf]
  const f32x4 zero = {0.f, 0.f, 0.f, 0.f};
#pragma unroll
  for (int a = 0; a < 8; a++)
#pragma unroll
    for (int b = 0; b < 4; b++) acc[a][b] = zero;

#define LDA(slot, a)                                                           \
  do {                                                                         \
    _Pragma("unroll") for (int m = 0; m < 4; ++m) {                            \
      afr[m][0] = *(const bf16x8*)(Ard + (slot) * 16384 +                      \
                                   ((a) * 64 + m * 16) * 64 + cs0);            \
      afr[m][1] = *(const bf16x8*)(Ard + (slot) * 16384 +                      \
                                   ((a) * 64 + m * 16) * 64 + cs1);            \
    }                                                                          \
  } while (0)
#define LDB2(slot, nlo)                                                        \
  do {                                                                         \
    _Pragma("unroll") for (int n = 0; n < 2; ++n) {                            \
      bfr[(nlo) + n][0] = *(const bf16x8*)(Brd + (slot) * 16384 +              \
                                           ((nlo) + n) * 16 * 64 + cs0);       \
      bfr[(nlo) + n][1] = *(const bf16x8*)(Brd + (slot) * 16384 +              \
                                           ((nlo) + n) * 16 * 64 + cs1);       \
    }                                                                          \
  } while (0)
#define MMQ(a, bh)                                                             \
  do {                                                                         \
    _Pragma("unroll") for (int m = 0; m < 4; ++m)                              \
        _Pragma("unroll") for (int n = 0; n < 2; ++n) {                        \
      acc[(a)*4 + m][(bh)*2 + n] = __builtin_amdgcn_mfma_f32_16x16x32_bf16(    \
          afr[m][0], bfr[(bh)*2 + n][0], acc[(a)*4 + m][(bh)*2 + n], 0, 0, 0); \
      acc[(a)*4 + m][(bh)*2 + n] = __builtin_amdgcn_mfma_f32_16x16x32_bf16(    \
          afr[m][1], bfr[(bh)*2 + n][1], acc[(a)*4 + m][(bh)*2 + n], 0, 0, 0); \
    }                                                                          \
  } while (0)

#define BAR asm volatile("s_barrier" ::: "memory")
#define WLG0 asm volatile("s_waitcnt lgkmcnt(0)" ::: "memory")
#define WLG8 asm volatile("s_waitcnt lgkmcnt(8)" ::: "memory")
#define WVM0 asm volatile("s_waitcnt vmcnt(0)" ::: "memory")
#define WVM4 asm volatile("s_waitcnt vmcnt(4)" ::: "memory")
#define SBAR0 __builtin_amdgcn_sched_barrier(0)
#define PRIO1 __builtin_amdgcn_s_setprio(1)
#define PRIO0 __builtin_amdgcn_s_setprio(0)

  // ---- prologue: tile0 complete into slot0, order-insensitive drain;
  // then tile1's two B halves -> exactly 4 outstanding entering the loop
  // (steady-state invariant; tile1's A halves staged at P1/P2 of iter 0).
  STG_A(0, 0, 0); STG_A(0, 1, 0); STG_B(0, 0, 0); STG_B(0, 1, 0);
  SBAR0;
  WVM0;  // tile0 fully landed, queue empty
  SBAR0;
  STG_B(1, 0, 1); STG_B(1, 1, 1);  // 4 outstanding
  SBAR0;
  BAR;

  // ---- main loop: 2 K-tiles / iter, 8 phases, one STG per phase.
#pragma unroll 1
  for (int i = 0; i < Kdim / 128; ++i) {
    const int t1 = 2 * i + 1;
    const int u0 = (2 * i + 2) & 63;  // wraps harmlessly on last iter
    const int u1 = (2 * i + 3) & 63;
    // P1: read s0 qa=0 + s0.B01; stage s1.A0(t1)   [sA[1][0] free: last
    //     read prev P7; t1.A0 drained by P4's vmcnt before P5 reads it]
    LDA(0, 0); LDB2(0, 0);
    STG_A(1, 0, t1);
    WLG8; BAR; WLG0; PRIO1; MMQ(0, 0); PRIO0; BAR;
    // P2: read s0.B23; stage s1.A1(t1)             [sA[1][1] free: prev P7]
    LDB2(0, 2);
    STG_A(1, 1, t1);
    BAR; WLG0; PRIO1; MMQ(0, 1); PRIO0; BAR;
    // P3: read s0 qa=1 (rows 64-127 of BOTH halves); stage s0.B0(u0)
    //     [sB[0][0] free: fully read by end P2]
    LDA(0, 1);
    STG_B(0, 0, u0);
    BAR; WLG0; PRIO1; MMQ(1, 1); PRIO0; BAR;
    // P4: stage s0.B1(u0); vmcnt(4): 12 outstanding -> drain oldest 8 =
    //     t1 {B0,B1 (prev P7/P8 or prologue), A0 (P1), A1 (P2)} -> slot1
    //     ready for P5.
    STG_B(0, 1, u0);
    BAR; PRIO1; MMQ(1, 0); PRIO0; WVM4; BAR;
    // P5: read s1 qa=0 + s1.B01; stage s0.A0(u0)   [sA[0][0] free: last
    //     read this iter P3]
    LDA(1, 0); LDB2(1, 0);
    STG_A(0, 0, u0);
    WLG8; BAR; WLG0; PRIO1; MMQ(0, 0); PRIO0; BAR;
    // P6: read s1.B23; stage s0.A1(u0)             [sA[0][1] free: P3]
    LDB2(1, 2);
    STG_A(0, 1, u0);
    BAR; WLG0; PRIO1; MMQ(0, 1); PRIO0; BAR;
    // P7: read s1 qa=1; stage s1.B0(u1)            [sB[1][0] free: end P6]
    LDA(1, 1);
    STG_B(1, 0, u1);
    BAR; WLG0; PRIO1; MMQ(1, 1); PRIO0; BAR;
    // P8: stage s1.B1(u1); vmcnt(4): drain oldest 8 = u0 {B0,B1,A0,A1
    //     (P3-P6)} -> slot0 ready for next iteration's P1.
    STG_B(1, 1, u1);
    BAR; PRIO1; MMQ(1, 0); PRIO0; WVM4; BAR;
  }

  // drain DMA before LDS dealloc / exit
  WVM0;

  // ---- epilogue: C = acc + bias (m97-verified C/D mapping)
#pragma unroll
  for (int nf = 0; nf < 4; ++nf) {
    const int n = bn0 + wn * 64 + nf * 16 + r15;
    const float bv = bias[n];
#pragma unroll
    for (int am = 0; am < 8; ++am) {
      const int mb = bm0 + wm * 128 + am * 16 + quad * 4;
#pragma unroll
      for (int r = 0; r < 4; ++r)
        C[(size_t)(mb + r) * Ndim + n] = acc[am][nf][r] + bv;
    }
  }
#undef STG_A
#undef STG_B
#undef LDA
#undef LDB2
#undef MMQ
#undef BAR
#undef WLG0
#undef WLG8
#undef WVM0
#undef WVM4
#undef SBAR0
#undef PRIO1
#undef PRIO0
}

// ---------------------------------------------------------------------------
// Fallback GEMM (only if ws_size < 96 MB): A fp32 packed in-loop (R1, 500us).
// ---------------------------------------------------------------------------
__global__ __launch_bounds__(256, 3) void gemm_pack(
    const float* __restrict__ A, const unsigned short* __restrict__ Bt,
    const float* __restrict__ bias, float* __restrict__ C) {
  __shared__ __align__(16) unsigned short lA[128 * 32];
  __shared__ __align__(16) unsigned short lB[128 * 32];
  const int tid = threadIdx.x, lane = tid & 63, wave = tid >> 6;
  const int bm0 = blockIdx.y * 128, bn0 = blockIdx.x * 128;
  const int wm = wave >> 1, wn = wave & 1;
  const int srow = lane >> 2, scol = (lane & 3) * 8;
  const unsigned short* Bg = Bt + (size_t)(bn0 + wave * 32 + srow) * Kdim + scol;
  unsigned short* lBp = &lB[wave * 32 * 32 + lane * 8];
  const int arow = wave * 16 + (lane >> 2);
  const int acol = (lane & 3) * 8;
  const float* Ag0 = A + (size_t)(bm0 + arow) * Kdim + acol;
  const float* Ag1 = Ag0 + (size_t)64 * Kdim;
  uint4* lAw0 = (uint4*)&lA[tid * 8];
  uint4* lAw1 = (uint4*)&lA[2048 + tid * 8];

  f32x4 acc[4][4];
  const f32x4 zero = {0.f, 0.f, 0.f, 0.f};
#pragma unroll
  for (int a = 0; a < 4; a++)
#pragma unroll
    for (int b = 0; b < 4; b++) acc[a][b] = zero;
  const int row = lane & 15, quad = lane >> 4;

  for (int k0 = 0; k0 < Kdim; k0 += 32) {
    __syncthreads();
    gl2lds16(Bg + k0, lBp);
    gl2lds16(Bg + k0 + 16 * Kdim, lBp + 16 * 32);
    float4 a0 = *(const float4*)(Ag0 + k0);
    float4 a1 = *(const float4*)(Ag0 + k0 + 4);
    float4 a2 = *(const float4*)(Ag1 + k0);
    float4 a3 = *(const float4*)(Ag1 + k0 + 4);
    uint4 w0 = {pk2bf_trunc(a0.x, a0.y), pk2bf_trunc(a0.z, a0.w),
                pk2bf_trunc(a1.x, a1.y), pk2bf_trunc(a1.z, a1.w)};
    uint4 w1 = {pk2bf_trunc(a2.x, a2.y), pk2bf_trunc(a2.z, a2.w),
                pk2bf_trunc(a3.x, a3.y), pk2bf_trunc(a3.z, a3.w)};
    *lAw0 = w0;
    *lAw1 = w1;
    __syncthreads();

    bf16x8 af[4], bfv[4];
#pragma unroll
    for (int mi = 0; mi < 4; mi++)
      af[mi] = *(const bf16x8*)&lA[(wm * 64 + mi * 16 + row) * 32 + quad * 8];
#pragma unroll
    for (int ni = 0; ni < 4; ni++)
      bfv[ni] = *(const bf16x8*)&lB[(wn * 64 + ni * 16 + row) * 32 + quad * 8];
#pragma unroll
    for (int mi = 0; mi < 4; mi++)
#pragma unroll
      for (int ni = 0; ni < 4; ni++)
        acc[mi][ni] = __builtin_amdgcn_mfma_f32_16x16x32_bf16(
            af[mi], bfv[ni], acc[mi][ni], 0, 0, 0);
  }
#pragma unroll
  for (int ni = 0; ni < 4; ni++) {
    const int n = bn0 + wn * 64 + ni * 16 + row;
    const float bv = bias[n];
#pragma unroll
    for (int mi = 0; mi < 4; mi++) {
      const int mbase = bm0 + wm * 64 + mi * 16 + quad * 4;
#pragma unroll
      for (int r = 0; r < 4; r++)
        C[(size_t)(mbase + r) * Ndim + n] = acc[mi][ni][r] + bv;
    }
  }
}

// ---------------------------------------------------------------------------
extern "C" void kernel_launch(void* const* d_in, const int* in_sizes, int n_in,
                              void* d_out, int out_size, void* d_ws,
                              size_t ws_size, hipStream_t stream) {
  const float* x = (const float*)d_in[0];
  const float* core0 = (const float*)d_in[1];
  const float* core1 = (const float*)d_in[2];
  const float* core2 = (const float*)d_in[3];
  const float* bias = (const float*)d_in[4];
  float* out = (float*)d_out;

  unsigned short* G = (unsigned short*)d_ws;
  const size_t G_BYTES = (size_t)4096 * 4096 * 2;
  const size_t X_BYTES = (size_t)Mdim * Kdim * 2;

  build_g<<<256, 256, 0, stream>>>(core0, core1, core2, G);

  if (ws_size >= G_BYTES + X_BYTES) {
    unsigned short* Xb = (unsigned short*)((char*)d_ws + G_BYTES);
    cvt_x<<<(Mdim * Kdim) / (256 * 8), 256, 0, stream>>>(x, Xb);
    gemm_8ph<<<(Mdim / 256) * (Ndim / 256), 512, 0, stream>>>(Xb, G, bias, out);
  } else {
    dim3 grid(Ndim / 128, Mdim / 128);
    gemm_pack<<<grid, 256, 0, stream>>>(x, G, bias, out);
  }
}